// Round 1
// baseline (434.450 us; speedup 1.0000x reference)
//
#include <hip/hip_runtime.h>
#include <math.h>

#define NWIN 4096
#define NHIST 131072
// ws word layout: [hist u32 x NHIST][finals f32 x 4*NWIN][sums f32 x 2]
#define WS_FINAL NHIST
#define WS_SUMS  (WS_FINAL + 4*NWIN)
#define WS_WORDS (WS_SUMS + 2)

#define SERVICE   1.0e8f   // CAPACITY * DELTA_T
#define CAPACITY_F 1.0e9f
#define DELTA_T_F 0.1f

// ---------------- K1: one pass over all rows ----------------
__global__ __launch_bounds__(1024)
void pl_k1(const float* __restrict__ logits, const int* __restrict__ y,
           const int* __restrict__ mask, const float* __restrict__ x_raw,
           const int* __restrict__ widx, const float* __restrict__ cw,
           float* __restrict__ ws_f, unsigned int* __restrict__ hist, int n)
{
    // LDS-privatized segment sums: [sum_p | sum_pr | sum_pd | count], 4096 each = 64 KB
    __shared__ float lds[4 * NWIN];
    const int tid = threadIdx.x;
    for (int s = tid; s < 4 * NWIN; s += 1024) lds[s] = 0.0f;
    __syncthreads();

    const float cw0 = cw[0], cw1 = cw[1];
    float acc_wnll = 0.0f, acc_w = 0.0f;

    const int stride = gridDim.x * 1024;
    for (int i = blockIdx.x * 1024 + tid; i < n; i += stride) {
        float2 lg = ((const float2*)logits)[i];
        int    yy = y[i];
        int    mk = mask[i];
        int    wi = widx[i];
        float4 xr = *((const float4*)(x_raw + 8 * (size_t)i));   // cols 0..3
        float  x4 = x_raw[8 * (size_t)i + 4];                    // col 4

        float l0 = lg.x, l1 = lg.y;
        float mx  = fmaxf(l0, l1);
        float lse = mx + logf(expf(l0 - mx) + expf(l1 - mx));
        float maskf = (mk != 0) ? 1.0f : 0.0f;
        float w   = (yy ? cw1 : cw0) * maskf;
        float nll = lse - (yy ? l1 : l0);
        acc_wnll += w * nll;
        acc_w    += w;

        if (mk != 0 && wi >= 0) {
            float p   = expf(l1 - lse);                 // softmax[:,1]
            int   seg = (wi < NWIN) ? wi : (NWIN - 1);
            float pr  = fmaxf(xr.w, 0.0f);              // pkt_rate  (col 3)
            float as  = fmaxf(x4, 0.0f) * 1000.0f;      // avg_size  (col 4)
            float dob = fmaxf(xr.z, 0.0f);              // d_obs     (col 2)
            unsafeAtomicAdd(&lds[seg],            p);
            unsafeAtomicAdd(&lds[NWIN + seg],     p * (pr * as));
            unsafeAtomicAdd(&lds[2 * NWIN + seg], p * dob);
            unsafeAtomicAdd(&lds[3 * NWIN + seg], 1.0f);
            int b = (int)(dob * (float)NHIST);
            b = (b < NHIST - 1) ? b : (NHIST - 1);
            b = (b > 0) ? b : 0;
            atomicAdd(&hist[b], 1u);
        }
    }

    // wave-level reduce for CE sums, one atomic per wave
    for (int o = 32; o > 0; o >>= 1) {
        acc_wnll += __shfl_down(acc_wnll, o, 64);
        acc_w    += __shfl_down(acc_w,    o, 64);
    }
    if ((tid & 63) == 0) {
        unsafeAtomicAdd(&ws_f[WS_SUMS],     acc_wnll);
        unsafeAtomicAdd(&ws_f[WS_SUMS + 1], acc_w);
    }

    __syncthreads();
    for (int s = tid; s < 4 * NWIN; s += 1024)
        unsafeAtomicAdd(&ws_f[WS_FINAL + s], lds[s]);
}

// ---------------- K2: quantile + parallel window scan + outputs ----------------
__global__ __launch_bounds__(1024)
void pl_k2(const unsigned int* __restrict__ hist, const float* __restrict__ ws_f,
           float* __restrict__ out)
{
    __shared__ float        sS[1024];
    __shared__ float        sM[1024];
    __shared__ unsigned int sC[1024];
    __shared__ float        sV[2];
    __shared__ float        sRed[3][16];

    const int tid = threadIdx.x;
    const int CHUNK = NHIST / 1024;   // 128 bins per thread

    // --- phase 1: histogram chunk counts + scan ---
    unsigned int c = 0;
    const int base = tid * CHUNK;
    {
        const uint4* h4 = (const uint4*)(hist + base);
        for (int j = 0; j < CHUNK / 4; ++j) {
            uint4 v = h4[j];
            c += v.x + v.y + v.z + v.w;
        }
    }
    sC[tid] = c;
    __syncthreads();
    for (int off = 1; off < 1024; off <<= 1) {
        unsigned int v = (tid >= off) ? sC[tid - off] : 0u;
        __syncthreads();
        sC[tid] += v;
        __syncthreads();
    }
    const unsigned int nv  = sC[1023];        // n_valid (exact)
    const unsigned int pre = sC[tid] - c;     // exclusive prefix

    if (tid == 0) { sV[0] = 1.0f; sV[1] = 1.0f; }
    __syncthreads();

    // quantile position (f32, matching reference)
    float nvf  = (float)nv;
    float pos  = 0.75f * (nvf - 1.0f);
    float fpos = floorf(pos);
    long  lo_l = (long)fpos;
    long  hi_l = (long)ceilf(pos);
    long  nmax = (nv > 0) ? (long)nv - 1 : 0;
    lo_l = lo_l < 0 ? 0 : (lo_l > nmax ? nmax : lo_l);
    hi_l = hi_l < 0 ? 0 : (hi_l > nmax ? nmax : hi_l);
    float frac = pos - fpos;

    if (nv > 0) {
        unsigned int lo = (unsigned int)lo_l, hi = (unsigned int)hi_l;
        if (lo >= pre && lo < pre + c) {
            unsigned int acc = pre;
            for (int j = 0; j < CHUNK; ++j) {
                acc += hist[base + j];
                if (lo < acc) { sV[0] = ((float)(base + j) + 0.5f) * (1.0f / (float)NHIST); break; }
            }
        }
        if (hi >= pre && hi < pre + c) {
            unsigned int acc = pre;
            for (int j = 0; j < CHUNK; ++j) {
                acc += hist[base + j];
                if (hi < acc) { sV[1] = ((float)(base + j) + 0.5f) * (1.0f / (float)NHIST); break; }
            }
        }
    }
    __syncthreads();
    float ref      = sV[0] * (1.0f - frac) + sV[1] * frac;
    float ref_dobs = fmaxf(ref, 1e-6f);
    float inv_ref  = 1.0f / ref_dobs;

    // --- phase 2: window recurrence as affine-max parallel scan ---
    // state update: q <- include ? max(q + a, 0) : q ; represent g(q)=max(q+S, M)
    const float* f_sp  = ws_f + WS_FINAL;
    const float* f_spr = f_sp + NWIN;
    const float* f_spd = f_spr + NWIN;
    const float* f_cnt = f_spd + NWIN;

    float va[4], vsp[4], vspr[4], vspd[4];
    bool  vinc[4];
    float S = 0.0f, M = -3.0e38f;     // identity
    const int w0 = tid * 4;
    for (int j = 0; j < 4; ++j) {
        int   wdx = w0 + j;
        float sp  = f_sp[wdx];
        float spr = f_spr[wdx];
        float spd = f_spd[wdx];
        float cnt = f_cnt[wdx];
        float a   = spr * DELTA_T_F - SERVICE;
        bool  inc = (cnt >= 1.0f) && (sp >= 1e-8f);
        va[j] = a; vsp[j] = sp; vspr[j] = spr; vspd[j] = spd; vinc[j] = inc;
        if (inc) { M = fmaxf(M + a, 0.0f); S = S + a; }   // compose f(q)=max(q+a,0) after current
    }
    sS[tid] = S; sM[tid] = M;
    __syncthreads();
    for (int off = 1; off < 1024; off <<= 1) {
        float vs = 0.0f, vm = -3.0e38f;
        if (tid >= off) { vs = sS[tid - off]; vm = sM[tid - off]; }
        __syncthreads();
        if (tid >= off) {
            float s2 = sS[tid], m2 = sM[tid];
            sS[tid] = vs + s2;
            sM[tid] = fmaxf(vm + s2, m2);   // (earlier)∘then(later)
        }
        __syncthreads();
    }
    float q = 0.0f;
    if (tid > 0) q = fmaxf(sS[tid - 1], sM[tid - 1]);   // exclusive prefix applied to q0=0

    float fsum = 0.0f, lsum = 0.0f, isum = 0.0f;
    for (int j = 0; j < 4; ++j) {
        float qn    = fmaxf(q + va[j], 0.0f);
        float dmean = vspd[j] / (vsp[j] + 1e-6f);
        float dsc   = dmean * inv_ref;
        float oq    = fmaxf(dsc - 1.0f, 0.0f) * SERVICE;
        float fw    = (qn - oq) / (SERVICE + 1e-6f);
        fw = fw * fw;
        float rho = vspr[j] / (CAPACITY_F + 1e-6f);
        rho = fminf(fmaxf(rho, 0.0f), 0.995f);
        float dth = 1.0f / (1.0f - rho + 1e-6f);
        float lt  = fmaxf(dth - dsc, 0.0f);
        if (vinc[j]) { fsum += fw; lsum += lt; isum += 1.0f; q = qn; }
    }

    for (int o = 32; o > 0; o >>= 1) {
        fsum += __shfl_down(fsum, o, 64);
        lsum += __shfl_down(lsum, o, 64);
        isum += __shfl_down(isum, o, 64);
    }
    const int wv = tid >> 6;
    if ((tid & 63) == 0) { sRed[0][wv] = fsum; sRed[1][wv] = lsum; sRed[2][wv] = isum; }
    __syncthreads();
    if (tid == 0) {
        float F = 0.0f, L = 0.0f, I = 0.0f;
        for (int k = 0; k < 16; ++k) { F += sRed[0][k]; L += sRed[1][k]; I += sRed[2][k]; }
        float l_data = ws_f[WS_SUMS] / ws_f[WS_SUMS + 1];
        float l_flow = (I > 0.0f) ? F / fmaxf(I, 1.0f) : 0.0f;
        float l_lat  = (I > 0.0f) ? L / fmaxf(I, 1.0f) : 0.0f;
        out[0] = l_data + 0.1f * l_flow + 0.1f * l_lat;
        out[1] = l_data;
        out[2] = l_flow;
        out[3] = l_lat;
    }
}

extern "C" void kernel_launch(void* const* d_in, const int* in_sizes, int n_in,
                              void* d_out, int out_size, void* d_ws, size_t ws_size,
                              hipStream_t stream) {
    const float* logits = (const float*)d_in[0];
    const int*   y      = (const int*)d_in[1];
    const int*   mask   = (const int*)d_in[2];   // bool -> int32 per harness convention (gamble; flip to u8 if absmax bad)
    const float* x_raw  = (const float*)d_in[3];
    const int*   widx   = (const int*)d_in[4];
    const float* cw     = (const float*)d_in[5];
    float* out = (float*)d_out;
    int n = in_sizes[1];   // N from y

    float*        ws_f = (float*)d_ws;
    unsigned int* hist = (unsigned int*)d_ws;

    hipMemsetAsync(d_ws, 0, (size_t)WS_WORDS * 4, stream);
    hipLaunchKernelGGL(pl_k1, dim3(256), dim3(1024), 0, stream,
                       logits, y, mask, x_raw, widx, cw, ws_f, hist, n);
    hipLaunchKernelGGL(pl_k2, dim3(1), dim3(1024), 0, stream,
                       hist, ws_f, out);
}

// Round 2
// 294.131 us; speedup vs baseline: 1.4771x; 1.4771x over previous
//
#include <hip/hip_runtime.h>
#include <math.h>

#define NWIN  4096
#define NHIST 8192
#define NBLK  256
#define SEGW  (4*NWIN)                       // 16384 seg-sum words
#define COPY_WORDS (SEGW + NHIST + 2)        // 24578
#define COPY_STRIDE 24608                    // padded; *4 = 98432 B (64B multiple)
#define FIN_OFF ((size_t)COPY_STRIDE * NBLK) // final region offset in words

#define SERVICE    1.0e8f   // CAPACITY * DELTA_T
#define CAPACITY_F 1.0e9f
#define DELTA_T_F  0.1f

// ---------------- K1: one pass over all rows, everything privatized ----------------
// MODE 1: write private copy (no global atomics).  MODE 0: atomic fallback (small ws).
template<int MODE>
__global__ __launch_bounds__(1024)
void pl_k1(const float* __restrict__ logits, const int* __restrict__ y,
           const int* __restrict__ mask, const float* __restrict__ x_raw,
           const int* __restrict__ widx, const float* __restrict__ cw,
           unsigned int* __restrict__ ws, int n)
{
    __shared__ float        lds[SEGW];     // [sum_p | sum_pr | sum_pd | count]
    __shared__ unsigned int lh[NHIST];
    __shared__ float        ce[2][16];
    const int tid = threadIdx.x;
    for (int s = tid; s < SEGW;  s += 1024) lds[s] = 0.0f;
    for (int s = tid; s < NHIST; s += 1024) lh[s]  = 0u;
    __syncthreads();

    const float cw0 = cw[0], cw1 = cw[1];
    float awn = 0.0f, aw = 0.0f;

    const int stride = gridDim.x * 1024;
    for (int i = blockIdx.x * 1024 + tid; i < n; i += stride) {
        float2 lg  = ((const float2*)logits)[i];
        int    yy  = y[i];
        int    mk  = mask[i];
        int    wi  = widx[i];
        float2 x23 = *(const float2*)(x_raw + 8 * (size_t)i + 2); // cols 2,3
        float  x4  = x_raw[8 * (size_t)i + 4];                    // col 4

        // 2-class CE: d = l0-l1; nll(y=1)=log(1+e^d); nll(y=0)=log(1+e^d)-d
        float d = lg.x - lg.y;
        float e = __expf(d);
        float t = __logf(1.0f + e);
        float nll = yy ? t : (t - d);
        float w   = (yy ? cw1 : cw0) * (mk ? 1.0f : 0.0f);
        awn += w * nll;
        aw  += w;

        if (mk && wi >= 0) {
            float p   = 1.0f / (1.0f + e);           // softmax[:,1]
            int   seg = (wi < NWIN) ? wi : (NWIN - 1);
            float dob = fmaxf(x23.x, 0.0f);          // d_obs    (col 2)
            float pr  = fmaxf(x23.y, 0.0f);          // pkt_rate (col 3)
            float as  = fmaxf(x4,    0.0f) * 1000.0f;// avg_size (col 4)
            unsafeAtomicAdd(&lds[seg],            p);
            unsafeAtomicAdd(&lds[NWIN + seg],     p * (pr * as));
            unsafeAtomicAdd(&lds[2 * NWIN + seg], p * dob);
            unsafeAtomicAdd(&lds[3 * NWIN + seg], 1.0f);
            int b = (int)(dob * (float)NHIST);
            b = (b < NHIST - 1) ? b : (NHIST - 1);
            b = (b > 0) ? b : 0;
            atomicAdd(&lh[b], 1u);
        }
    }

    // CE partial: wave shuffle-reduce -> LDS
    for (int o = 32; o > 0; o >>= 1) {
        awn += __shfl_down(awn, o, 64);
        aw  += __shfl_down(aw,  o, 64);
    }
    if ((tid & 63) == 0) { ce[0][tid >> 6] = awn; ce[1][tid >> 6] = aw; }
    __syncthreads();

    if (MODE == 1) {
        // plain coalesced stores to this block's private copy region
        unsigned int* cb  = ws + (size_t)blockIdx.x * COPY_STRIDE;
        float*        cbf = (float*)cb;
        for (int s = tid; s < SEGW;  s += 1024) cbf[s] = lds[s];
        for (int s = tid; s < NHIST; s += 1024) cb[SEGW + s] = lh[s];
        if (tid == 0) {
            float A = 0.0f, B = 0.0f;
            for (int k = 0; k < 16; ++k) { A += ce[0][k]; B += ce[1][k]; }
            cbf[SEGW + NHIST]     = A;
            cbf[SEGW + NHIST + 1] = B;
        }
    } else {
        // fallback: atomic flush into final region at ws[0] (pre-zeroed)
        float*        finf = (float*)ws;
        unsigned int* finh = ws + SEGW;
        for (int s = tid; s < SEGW;  s += 1024) if (lds[s] != 0.0f) unsafeAtomicAdd(&finf[s], lds[s]);
        for (int s = tid; s < NHIST; s += 1024) if (lh[s]) atomicAdd(&finh[s], lh[s]);
        if (tid == 0) {
            float A = 0.0f, B = 0.0f;
            for (int k = 0; k < 16; ++k) { A += ce[0][k]; B += ce[1][k]; }
            unsafeAtomicAdd(&finf[SEGW + NHIST],     A);
            unsafeAtomicAdd(&finf[SEGW + NHIST + 1], B);
        }
    }
}

// ---------------- Kmid: reduce the 256 private copies into the final region ----------------
__global__ __launch_bounds__(256)
void pl_kmid(const unsigned int* __restrict__ ws, unsigned int* __restrict__ fin)
{
    int j = blockIdx.x * 256 + threadIdx.x;
    if (j >= COPY_WORDS) return;
    if (j < SEGW || j >= SEGW + NHIST) {
        float s0 = 0.f, s1 = 0.f, s2 = 0.f, s3 = 0.f;
        const float* wf = (const float*)ws;
        for (int c = 0; c < NBLK; c += 4) {
            s0 += wf[(size_t)(c + 0) * COPY_STRIDE + j];
            s1 += wf[(size_t)(c + 1) * COPY_STRIDE + j];
            s2 += wf[(size_t)(c + 2) * COPY_STRIDE + j];
            s3 += wf[(size_t)(c + 3) * COPY_STRIDE + j];
        }
        ((float*)fin)[j] = (s0 + s1) + (s2 + s3);
    } else {
        unsigned int s0 = 0, s1 = 0, s2 = 0, s3 = 0;
        for (int c = 0; c < NBLK; c += 4) {
            s0 += ws[(size_t)(c + 0) * COPY_STRIDE + j];
            s1 += ws[(size_t)(c + 1) * COPY_STRIDE + j];
            s2 += ws[(size_t)(c + 2) * COPY_STRIDE + j];
            s3 += ws[(size_t)(c + 3) * COPY_STRIDE + j];
        }
        fin[j] = (s0 + s1) + (s2 + s3);
    }
}

// ---------------- K2: quantile + parallel window scan + outputs ----------------
__global__ __launch_bounds__(1024)
void pl_k2(const unsigned int* __restrict__ fin, float* __restrict__ out)
{
    __shared__ float        sS[1024];
    __shared__ float        sM[1024];
    __shared__ unsigned int sC[1024];
    __shared__ float        sV[2];
    __shared__ float        sRed[3][16];

    const int tid = threadIdx.x;
    const unsigned int* hist = fin + SEGW;
    const int CHUNK = NHIST / 1024;   // 8 bins per thread

    // --- phase 1: histogram chunk counts + block scan ---
    unsigned int hv[CHUNK];
    unsigned int c = 0;
    const int base = tid * CHUNK;
    {
        const uint4* h4 = (const uint4*)(hist + base);
        uint4 a = h4[0], b = h4[1];
        hv[0]=a.x; hv[1]=a.y; hv[2]=a.z; hv[3]=a.w;
        hv[4]=b.x; hv[5]=b.y; hv[6]=b.z; hv[7]=b.w;
        for (int j = 0; j < CHUNK; ++j) c += hv[j];
    }
    sC[tid] = c;
    __syncthreads();
    for (int off = 1; off < 1024; off <<= 1) {
        unsigned int v = (tid >= off) ? sC[tid - off] : 0u;
        __syncthreads();
        sC[tid] += v;
        __syncthreads();
    }
    const unsigned int nv  = sC[1023];        // n_valid (exact)
    const unsigned int pre = sC[tid] - c;     // exclusive prefix

    if (tid == 0) { sV[0] = 1.0f; sV[1] = 1.0f; }
    __syncthreads();

    float nvf  = (float)nv;
    float pos  = 0.75f * (nvf - 1.0f);
    float fpos = floorf(pos);
    long  lo_l = (long)fpos;
    long  hi_l = (long)ceilf(pos);
    long  nmax = (nv > 0) ? (long)nv - 1 : 0;
    lo_l = lo_l < 0 ? 0 : (lo_l > nmax ? nmax : lo_l);
    hi_l = hi_l < 0 ? 0 : (hi_l > nmax ? nmax : hi_l);
    float frac = pos - fpos;

    if (nv > 0) {
        unsigned int lo = (unsigned int)lo_l, hi = (unsigned int)hi_l;
        if (lo >= pre && lo < pre + c) {
            unsigned int acc = pre;
            for (int j = 0; j < CHUNK; ++j) {
                acc += hv[j];
                if (lo < acc) { sV[0] = ((float)(base + j) + 0.5f) * (1.0f / (float)NHIST); break; }
            }
        }
        if (hi >= pre && hi < pre + c) {
            unsigned int acc = pre;
            for (int j = 0; j < CHUNK; ++j) {
                acc += hv[j];
                if (hi < acc) { sV[1] = ((float)(base + j) + 0.5f) * (1.0f / (float)NHIST); break; }
            }
        }
    }
    __syncthreads();
    float ref      = sV[0] * (1.0f - frac) + sV[1] * frac;
    float ref_dobs = fmaxf(ref, 1e-6f);
    float inv_ref  = 1.0f / ref_dobs;

    // --- phase 2: window recurrence as affine-max parallel scan ---
    const float* f_sp  = (const float*)fin;
    const float* f_spr = f_sp + NWIN;
    const float* f_spd = f_spr + NWIN;
    const float* f_cnt = f_spd + NWIN;

    float va[4], vsp[4], vspr[4], vspd[4];
    bool  vinc[4];
    float S = 0.0f, M = -3.0e38f;     // identity
    const int w0 = tid * 4;
    for (int j = 0; j < 4; ++j) {
        int   wdx = w0 + j;
        float sp  = f_sp[wdx];
        float spr = f_spr[wdx];
        float spd = f_spd[wdx];
        float cnt = f_cnt[wdx];
        float a   = spr * DELTA_T_F - SERVICE;
        bool  inc = (cnt >= 1.0f) && (sp >= 1e-8f);
        va[j] = a; vsp[j] = sp; vspr[j] = spr; vspd[j] = spd; vinc[j] = inc;
        if (inc) { M = fmaxf(M + a, 0.0f); S = S + a; }
    }
    sS[tid] = S; sM[tid] = M;
    __syncthreads();
    for (int off = 1; off < 1024; off <<= 1) {
        float vs = 0.0f, vm = -3.0e38f;
        if (tid >= off) { vs = sS[tid - off]; vm = sM[tid - off]; }
        __syncthreads();
        if (tid >= off) {
            float s2 = sS[tid], m2 = sM[tid];
            sS[tid] = vs + s2;
            sM[tid] = fmaxf(vm + s2, m2);
        }
        __syncthreads();
    }
    float q = 0.0f;
    if (tid > 0) q = fmaxf(sS[tid - 1], sM[tid - 1]);

    float fsum = 0.0f, lsum = 0.0f, isum = 0.0f;
    for (int j = 0; j < 4; ++j) {
        float qn    = fmaxf(q + va[j], 0.0f);
        float dmean = vspd[j] / (vsp[j] + 1e-6f);
        float dsc   = dmean * inv_ref;
        float oq    = fmaxf(dsc - 1.0f, 0.0f) * SERVICE;
        float fw    = (qn - oq) / (SERVICE + 1e-6f);
        fw = fw * fw;
        float rho = vspr[j] / (CAPACITY_F + 1e-6f);
        rho = fminf(fmaxf(rho, 0.0f), 0.995f);
        float dth = 1.0f / (1.0f - rho + 1e-6f);
        float lt  = fmaxf(dth - dsc, 0.0f);
        if (vinc[j]) { fsum += fw; lsum += lt; isum += 1.0f; q = qn; }
    }

    for (int o = 32; o > 0; o >>= 1) {
        fsum += __shfl_down(fsum, o, 64);
        lsum += __shfl_down(lsum, o, 64);
        isum += __shfl_down(isum, o, 64);
    }
    const int wv = tid >> 6;
    if ((tid & 63) == 0) { sRed[0][wv] = fsum; sRed[1][wv] = lsum; sRed[2][wv] = isum; }
    __syncthreads();
    if (tid == 0) {
        float F = 0.0f, L = 0.0f, I = 0.0f;
        for (int k = 0; k < 16; ++k) { F += sRed[0][k]; L += sRed[1][k]; I += sRed[2][k]; }
        const float* ff = (const float*)fin;
        float l_data = ff[SEGW + NHIST] / ff[SEGW + NHIST + 1];
        float l_flow = (I > 0.0f) ? F / fmaxf(I, 1.0f) : 0.0f;
        float l_lat  = (I > 0.0f) ? L / fmaxf(I, 1.0f) : 0.0f;
        out[0] = l_data + 0.1f * l_flow + 0.1f * l_lat;
        out[1] = l_data;
        out[2] = l_flow;
        out[3] = l_lat;
    }
}

extern "C" void kernel_launch(void* const* d_in, const int* in_sizes, int n_in,
                              void* d_out, int out_size, void* d_ws, size_t ws_size,
                              hipStream_t stream) {
    const float* logits = (const float*)d_in[0];
    const int*   y      = (const int*)d_in[1];
    const int*   mask   = (const int*)d_in[2];
    const float* x_raw  = (const float*)d_in[3];
    const int*   widx   = (const int*)d_in[4];
    const float* cw     = (const float*)d_in[5];
    float* out = (float*)d_out;
    int n = in_sizes[1];   // N from y

    unsigned int* ws = (unsigned int*)d_ws;
    size_t need = (FIN_OFF + COPY_WORDS) * 4;

    if (ws_size >= need) {
        // atomic-free path: private copies + tree reduce
        hipLaunchKernelGGL((pl_k1<1>), dim3(NBLK), dim3(1024), 0, stream,
                           logits, y, mask, x_raw, widx, cw, ws, n);
        hipLaunchKernelGGL(pl_kmid, dim3((COPY_WORDS + 255) / 256), dim3(256), 0, stream,
                           ws, ws + FIN_OFF);
        hipLaunchKernelGGL(pl_k2, dim3(1), dim3(1024), 0, stream,
                           ws + FIN_OFF, out);
    } else {
        // fallback: atomic flush into ws[0]
        hipMemsetAsync(d_ws, 0, (size_t)COPY_WORDS * 4, stream);
        hipLaunchKernelGGL((pl_k1<0>), dim3(NBLK), dim3(1024), 0, stream,
                           logits, y, mask, x_raw, widx, cw, ws, n);
        hipLaunchKernelGGL(pl_k2, dim3(1), dim3(1024), 0, stream,
                           ws, out);
    }
}

// Round 3
// 278.838 us; speedup vs baseline: 1.5581x; 1.0548x over previous
//
#include <hip/hip_runtime.h>
#include <math.h>

#define NWIN  4096
#define NHIST 7168                    // 7*1024; float bins (counts exact < 2^24)
#define SEGW  (3*NWIN)                // [sum_p | sum_pr | sum_pd]  (count removed)
#define CE_OFF (SEGW + NHIST)        // 19456: 16 wnll + 16 w partials
#define CW    (CE_OFF + 32)          // 19488 words per copy
#define CWP   19520                  // padded stride (78080 B; 305*256B -> odd channel spread)
#define MAXBLK 512

#define SERVICE    1.0e8f   // CAPACITY * DELTA_T
#define CAPACITY_F 1.0e9f
#define DELTA_T_F  0.1f

// ---------------- K1: one pass over all rows ----------------
// MODE 1: plain stores to private copy. MODE 0: atomic fallback into fin at ws[0].
template<int MODE>
__global__ __launch_bounds__(1024, 8)
void pl_k1(const float* __restrict__ logits, const int* __restrict__ y,
           const int* __restrict__ mask, const float* __restrict__ x_raw,
           const int* __restrict__ widx, const float* __restrict__ cw,
           float* __restrict__ ws, int n)
{
    __shared__ float lds[SEGW + NHIST];   // 77824 B -> 2 blocks/CU
    const int tid = threadIdx.x;
    for (int s = tid; s < SEGW + NHIST; s += 1024) lds[s] = 0.0f;
    __syncthreads();

    const float cw0 = cw[0], cw1 = cw[1];
    float awn = 0.0f, aw = 0.0f;

    const int stride = gridDim.x * 1024;
    for (int i = blockIdx.x * 1024 + tid; i < n; i += stride) {
        float2 lg  = ((const float2*)logits)[i];
        int    yy  = y[i];
        int    mk  = mask[i];
        int    wi  = widx[i];
        float2 x23 = *(const float2*)(x_raw + 8 * (size_t)i + 2); // cols 2,3
        float  x4  = x_raw[8 * (size_t)i + 4];                    // col 4

        // 2-class CE: d = l0-l1; nll(y=1)=log(1+e^d); nll(y=0)=log(1+e^d)-d
        float d = lg.x - lg.y;
        float e = __expf(d);
        float t = __logf(1.0f + e);
        float nll = yy ? t : (t - d);
        float w   = (yy ? cw1 : cw0) * (mk ? 1.0f : 0.0f);
        awn += w * nll;
        aw  += w;

        if (mk && wi >= 0) {
            float p   = 1.0f / (1.0f + e);            // softmax[:,1]
            int   seg = (wi < NWIN) ? wi : (NWIN - 1);
            float dob = fmaxf(x23.x, 0.0f);           // d_obs    (col 2)
            float pr  = fmaxf(x23.y, 0.0f);           // pkt_rate (col 3)
            float as  = fmaxf(x4,    0.0f) * 1000.0f; // avg_size (col 4)
            unsafeAtomicAdd(&lds[seg],            p);
            unsafeAtomicAdd(&lds[NWIN + seg],     p * (pr * as));
            unsafeAtomicAdd(&lds[2 * NWIN + seg], p * dob);
            int b = (int)(dob * (float)NHIST);
            b = (b < NHIST - 1) ? b : (NHIST - 1);
            b = (b > 0) ? b : 0;
            unsafeAtomicAdd(&lds[SEGW + b], 1.0f);
        }
    }

    // CE partial: wave shuffle-reduce
    for (int o = 32; o > 0; o >>= 1) {
        awn += __shfl_down(awn, o, 64);
        aw  += __shfl_down(aw,  o, 64);
    }
    __syncthreads();

    if (MODE == 1) {
        float* cb = ws + (size_t)blockIdx.x * CWP;
        for (int s = tid; s < SEGW + NHIST; s += 1024) cb[s] = lds[s];
        if ((tid & 63) == 0) {
            cb[CE_OFF      + (tid >> 6)] = awn;
            cb[CE_OFF + 16 + (tid >> 6)] = aw;
        }
    } else {
        for (int s = tid; s < SEGW + NHIST; s += 1024)
            if (lds[s] != 0.0f) unsafeAtomicAdd(&ws[s], lds[s]);
        if ((tid & 63) == 0) {
            unsafeAtomicAdd(&ws[CE_OFF      + (tid >> 6)], awn);
            unsafeAtomicAdd(&ws[CE_OFF + 16 + (tid >> 6)], aw);
        }
    }
}

// ---------------- Kmid: reduce C private copies into fin ----------------
// block = 64 output words x 4 copy-groups; each thread sums C/4 copies.
__global__ __launch_bounds__(256)
void pl_kmid(const float* __restrict__ ws, float* __restrict__ fin, int C)
{
    __shared__ float sRed[256];
    const int j   = threadIdx.x & 63;
    const int g   = threadIdx.x >> 6;
    const int idx = blockIdx.x * 64 + j;

    float a0 = 0.f, a1 = 0.f, a2 = 0.f, a3 = 0.f;
    if (idx < CW) {
        int c = g;
        for (; c + 12 < C; c += 16) {
            a0 += ws[(size_t)(c)      * CWP + idx];
            a1 += ws[(size_t)(c + 4)  * CWP + idx];
            a2 += ws[(size_t)(c + 8)  * CWP + idx];
            a3 += ws[(size_t)(c + 12) * CWP + idx];
        }
        for (; c < C; c += 4) a0 += ws[(size_t)c * CWP + idx];
    }
    sRed[threadIdx.x] = (a0 + a1) + (a2 + a3);
    __syncthreads();
    if (g == 0 && idx < CW)
        fin[idx] = (sRed[j] + sRed[64 + j]) + (sRed[128 + j] + sRed[192 + j]);
}

// ---------------- K2: quantile + parallel window scan + outputs ----------------
__global__ __launch_bounds__(1024)
void pl_k2(const float* __restrict__ fin, float* __restrict__ out)
{
    __shared__ float        sS[1024];
    __shared__ float        sM[1024];
    __shared__ unsigned int sC[1024];
    __shared__ float        sV[2];
    __shared__ float        sRed[3][16];

    const int tid = threadIdx.x;
    const float* hist = fin + SEGW;
    const int CHUNK = NHIST / 1024;   // 7 bins per thread

    // --- phase 1: histogram chunk counts + block scan ---
    unsigned int hv[CHUNK];
    unsigned int c = 0;
    const int base = tid * CHUNK;
    for (int j = 0; j < CHUNK; ++j) { hv[j] = (unsigned int)hist[base + j]; c += hv[j]; }
    sC[tid] = c;
    __syncthreads();
    for (int off = 1; off < 1024; off <<= 1) {
        unsigned int v = (tid >= off) ? sC[tid - off] : 0u;
        __syncthreads();
        sC[tid] += v;
        __syncthreads();
    }
    const unsigned int nv  = sC[1023];        // n_valid (exact)
    const unsigned int pre = sC[tid] - c;     // exclusive prefix

    if (tid == 0) { sV[0] = 1.0f; sV[1] = 1.0f; }
    __syncthreads();

    float nvf  = (float)nv;
    float pos  = 0.75f * (nvf - 1.0f);
    float fpos = floorf(pos);
    long  lo_l = (long)fpos;
    long  hi_l = (long)ceilf(pos);
    long  nmax = (nv > 0) ? (long)nv - 1 : 0;
    lo_l = lo_l < 0 ? 0 : (lo_l > nmax ? nmax : lo_l);
    hi_l = hi_l < 0 ? 0 : (hi_l > nmax ? nmax : hi_l);
    float frac = pos - fpos;

    if (nv > 0) {
        unsigned int lo = (unsigned int)lo_l, hi = (unsigned int)hi_l;
        if (lo >= pre && lo < pre + c) {
            unsigned int acc = pre;
            for (int j = 0; j < CHUNK; ++j) {
                acc += hv[j];
                if (lo < acc) { sV[0] = ((float)(base + j) + 0.5f) * (1.0f / (float)NHIST); break; }
            }
        }
        if (hi >= pre && hi < pre + c) {
            unsigned int acc = pre;
            for (int j = 0; j < CHUNK; ++j) {
                acc += hv[j];
                if (hi < acc) { sV[1] = ((float)(base + j) + 0.5f) * (1.0f / (float)NHIST); break; }
            }
        }
    }
    __syncthreads();
    float ref      = sV[0] * (1.0f - frac) + sV[1] * frac;
    float ref_dobs = fmaxf(ref, 1e-6f);
    float inv_ref  = 1.0f / ref_dobs;

    // --- phase 2: window recurrence as affine-max parallel scan ---
    const float* f_sp  = fin;
    const float* f_spr = fin + NWIN;
    const float* f_spd = fin + 2 * NWIN;

    float va[4], vsp[4], vspr[4], vspd[4];
    bool  vinc[4];
    float S = 0.0f, M = -3.0e38f;     // identity
    const int w0 = tid * 4;
    for (int j = 0; j < 4; ++j) {
        int   wdx = w0 + j;
        float sp  = f_sp[wdx];
        float spr = f_spr[wdx];
        float spd = f_spd[wdx];
        float a   = spr * DELTA_T_F - SERVICE;
        bool  inc = (sp >= 1e-8f);   // == (cnt>=1 && sp>=1e-8): sp>=1e-8 implies cnt>=1
        va[j] = a; vsp[j] = sp; vspr[j] = spr; vspd[j] = spd; vinc[j] = inc;
        if (inc) { M = fmaxf(M + a, 0.0f); S = S + a; }
    }
    sS[tid] = S; sM[tid] = M;
    __syncthreads();
    for (int off = 1; off < 1024; off <<= 1) {
        float vs = 0.0f, vm = -3.0e38f;
        if (tid >= off) { vs = sS[tid - off]; vm = sM[tid - off]; }
        __syncthreads();
        if (tid >= off) {
            float s2 = sS[tid], m2 = sM[tid];
            sS[tid] = vs + s2;
            sM[tid] = fmaxf(vm + s2, m2);
        }
        __syncthreads();
    }
    float q = 0.0f;
    if (tid > 0) q = fmaxf(sS[tid - 1], sM[tid - 1]);

    float fsum = 0.0f, lsum = 0.0f, isum = 0.0f;
    for (int j = 0; j < 4; ++j) {
        float qn    = fmaxf(q + va[j], 0.0f);
        float dmean = vspd[j] / (vsp[j] + 1e-6f);
        float dsc   = dmean * inv_ref;
        float oq    = fmaxf(dsc - 1.0f, 0.0f) * SERVICE;
        float fw    = (qn - oq) / (SERVICE + 1e-6f);
        fw = fw * fw;
        float rho = vspr[j] / (CAPACITY_F + 1e-6f);
        rho = fminf(fmaxf(rho, 0.0f), 0.995f);
        float dth = 1.0f / (1.0f - rho + 1e-6f);
        float lt  = fmaxf(dth - dsc, 0.0f);
        if (vinc[j]) { fsum += fw; lsum += lt; isum += 1.0f; q = qn; }
    }

    for (int o = 32; o > 0; o >>= 1) {
        fsum += __shfl_down(fsum, o, 64);
        lsum += __shfl_down(lsum, o, 64);
        isum += __shfl_down(isum, o, 64);
    }
    const int wv = tid >> 6;
    if ((tid & 63) == 0) { sRed[0][wv] = fsum; sRed[1][wv] = lsum; sRed[2][wv] = isum; }
    __syncthreads();
    if (tid == 0) {
        float F = 0.0f, L = 0.0f, I = 0.0f;
        float A = 0.0f, B = 0.0f;
        for (int k = 0; k < 16; ++k) {
            F += sRed[0][k]; L += sRed[1][k]; I += sRed[2][k];
            A += fin[CE_OFF + k]; B += fin[CE_OFF + 16 + k];
        }
        float l_data = A / B;
        float l_flow = (I > 0.0f) ? F / fmaxf(I, 1.0f) : 0.0f;
        float l_lat  = (I > 0.0f) ? L / fmaxf(I, 1.0f) : 0.0f;
        out[0] = l_data + 0.1f * l_flow + 0.1f * l_lat;
        out[1] = l_data;
        out[2] = l_flow;
        out[3] = l_lat;
    }
}

extern "C" void kernel_launch(void* const* d_in, const int* in_sizes, int n_in,
                              void* d_out, int out_size, void* d_ws, size_t ws_size,
                              hipStream_t stream) {
    const float* logits = (const float*)d_in[0];
    const int*   y      = (const int*)d_in[1];
    const int*   mask   = (const int*)d_in[2];
    const float* x_raw  = (const float*)d_in[3];
    const int*   widx   = (const int*)d_in[4];
    const float* cw     = (const float*)d_in[5];
    float* out = (float*)d_out;
    int n = in_sizes[1];   // N from y

    float* ws = (float*)d_ws;
    size_t words = ws_size / 4;
    long   cap   = (words > CW) ? (long)((words - CW) / CWP) : 0;
    int    nblk  = (cap > MAXBLK) ? MAXBLK : (int)cap;

    if (nblk >= 64) {
        float* fin = ws + (size_t)nblk * CWP;
        hipLaunchKernelGGL((pl_k1<1>), dim3(nblk), dim3(1024), 0, stream,
                           logits, y, mask, x_raw, widx, cw, ws, n);
        hipLaunchKernelGGL(pl_kmid, dim3((CW + 63) / 64), dim3(256), 0, stream,
                           ws, fin, nblk);
        hipLaunchKernelGGL(pl_k2, dim3(1), dim3(1024), 0, stream,
                           fin, out);
    } else {
        hipMemsetAsync(d_ws, 0, (size_t)CW * 4, stream);
        hipLaunchKernelGGL((pl_k1<0>), dim3(256), dim3(1024), 0, stream,
                           logits, y, mask, x_raw, widx, cw, ws, n);
        hipLaunchKernelGGL(pl_k2, dim3(1), dim3(1024), 0, stream,
                           ws, out);
    }
}